// Round 9
// baseline (148.201 us; speedup 1.0000x reference)
//
#include <hip/hip_runtime.h>
#include <hip/hip_bf16.h>

// GCN 2-layer: out = Â·relu(Â·X·W0 + b0)·W1 + b1,  Â = D^-1/2 (A+I) D^-1/2
// GEMM-first, bucketed one-pass CSR (64-slot buckets), bf16 gather buffers.
// R9 experiment: XCD-partitioned CSR build — block bid handles dst range
// bid&7 (blockIdx%8 -> XCD heuristic), so every cnt/col line is written by
// one XCD only (no cross-XCD partial-line churn). Padded counters (16B).
// Build unfused this round for clean per-kernel counters.

typedef __attribute__((ext_vector_type(8))) unsigned short ushort8;

#define BUCKET 64  // per-node slot capacity; Poisson(16) tail P(>63) ~ 1e-19

__device__ inline float bf2f(unsigned short u) {
    return __uint_as_float(((unsigned)u) << 16);
}
__device__ inline unsigned short f2bf(float f) {
    unsigned u = __float_as_uint(f);
    return (unsigned short)((u + 0x7fffu + ((u >> 16) & 1u)) >> 16);  // RNE
}

__global__ void k_zero(int* __restrict__ p, int m) {
    int i = blockIdx.x * 256 + threadIdx.x;
    if (i < m) p[i] = 0;
}

// ---------------- XCD-partitioned bucket build ----------------
// block bid: range r = bid&7 (dst in [r*n/8,(r+1)*n/8)), chunk = bid>>3.
// Streams the whole chunk, keeps only in-range edges -> cnt/col lines are
// single-XCD-owned (if blockIdx%8 -> XCD round-robin holds).

__global__ __launch_bounds__(256) void k_build(
    const int* __restrict__ src, const int* __restrict__ dst,
    int* __restrict__ cntP, unsigned short* __restrict__ col,
    int nE, int n) {
    const int r = blockIdx.x & 7;
    const int chunk = blockIdx.x >> 3;
    const int lo = (int)(((long long)r * n) >> 3);
    const int hi = (int)(((long long)(r + 1) * n) >> 3);
    int e0 = (chunk * 256 + threadIdx.x) * 8;
    if (e0 + 7 < nE) {
        int4 da = *reinterpret_cast<const int4*>(dst + e0);
        int4 db = *reinterpret_cast<const int4*>(dst + e0 + 4);
        int4 sa = *reinterpret_cast<const int4*>(src + e0);
        int4 sb = *reinterpret_cast<const int4*>(src + e0 + 4);
#define PROC(d, s)                                                    \
        if ((d) >= lo && (d) < hi) {                                  \
            int rk = atomicAdd(&cntP[(d) * 4], 1);                    \
            if (rk < BUCKET) col[(d) * BUCKET + rk] = (unsigned short)(s); \
        }
        PROC(da.x, sa.x) PROC(da.y, sa.y) PROC(da.z, sa.z) PROC(da.w, sa.w)
        PROC(db.x, sb.x) PROC(db.y, sb.y) PROC(db.z, sb.z) PROC(db.w, sb.w)
    } else {
        for (int e = e0; e < nE; ++e) {
            int d = dst[e];
            int s = src[e];
            PROC(d, s)
        }
#undef PROC
    }
}

// densify padded counters for the agg kernels
__global__ void k_pack(const int* __restrict__ cntP, int* __restrict__ cnt, int n) {
    int i = blockIdx.x * 256 + threadIdx.x;
    if (i < n) cnt[i] = cntP[i * 4];
}

// ---------------- GEMM: C[n x COLS](bf16) = A[n x 128](f32) @ W[128 x COLS](f32) ----

template <int COLS>
__global__ __launch_bounds__(256) void k_gemm(const float* __restrict__ A,
                                              const float* __restrict__ W,
                                              unsigned short* __restrict__ C, int n) {
    constexpr int MT = 8192 / COLS;
    constexpr int CG = COLS / 8;
    __shared__ float As[MT][33];
    __shared__ float Ws[32][COLS];
    const int tx = threadIdx.x;
    const int cg = tx % CG;
    const int rg = tx / CG;
    const int row0 = blockIdx.x * MT;
    float acc[4][8] = {};

    for (int k0 = 0; k0 < 128; k0 += 32) {
        for (int idx = tx; idx < MT * 8; idx += 256) {
            int r = idx >> 3, c4 = (idx & 7) * 4;
            int gr = row0 + r;
            float4 v = make_float4(0.f, 0.f, 0.f, 0.f);
            if (gr < n) v = *reinterpret_cast<const float4*>(A + (size_t)gr * 128 + k0 + c4);
            As[r][c4 + 0] = v.x; As[r][c4 + 1] = v.y;
            As[r][c4 + 2] = v.z; As[r][c4 + 3] = v.w;
        }
        for (int idx = tx; idx < 32 * COLS / 4; idx += 256) {
            int k = idx / (COLS / 4), c4 = (idx % (COLS / 4)) * 4;
            *reinterpret_cast<float4*>(&Ws[k][c4]) =
                *reinterpret_cast<const float4*>(W + (size_t)(k0 + k) * COLS + c4);
        }
        __syncthreads();
#pragma unroll 8
        for (int kk = 0; kk < 32; ++kk) {
            float ar[4];
#pragma unroll
            for (int i = 0; i < 4; ++i) ar[i] = As[rg * 4 + i][kk];
            const float* wrow = &Ws[kk][cg * 8];
            float4 wA = *reinterpret_cast<const float4*>(wrow);
            float4 wB = *reinterpret_cast<const float4*>(wrow + 4);
            float w[8] = {wA.x, wA.y, wA.z, wA.w, wB.x, wB.y, wB.z, wB.w};
#pragma unroll
            for (int i = 0; i < 4; ++i)
#pragma unroll
                for (int j = 0; j < 8; ++j)
                    acc[i][j] += ar[i] * w[j];
        }
        __syncthreads();
    }
#pragma unroll
    for (int i = 0; i < 4; ++i) {
        int gr = row0 + rg * 4 + i;
        if (gr < n) {
            ushort8 o;
#pragma unroll
            for (int j = 0; j < 8; ++j) o[j] = f2bf(acc[i][j]);
            *reinterpret_cast<ushort8*>(C + (size_t)gr * COLS + cg * 8) = o;
        }
    }
}

// ---------------- fused layer-1 agg + layer-2 GEMM ----------------

__global__ __launch_bounds__(512) void k_aggmm(
    const unsigned short* __restrict__ V,   // XW bf16 [n][128]
    const int* __restrict__ cnt,
    const unsigned short* __restrict__ col,
    const float* __restrict__ b0v,          // [128]
    const float* __restrict__ W1,           // [128][64] f32
    unsigned short* __restrict__ HW,        // [n][64] bf16
    int n) {
    __shared__ float W1s[128 * 64];   // 32 KB
    __shared__ float hS[32][132];     // 16.5 KB
    const int tx = threadIdx.x;

    for (int i = tx; i < 128 * 64 / 4; i += 512)
        reinterpret_cast<float4*>(W1s)[i] = reinterpret_cast<const float4*>(W1)[i];

    const int ln   = tx >> 4;
    const int d8   = (tx & 15) * 8;
    const int node = blockIdx.x * 32 + ln;

    if (node < n) {
        int degc = cnt[node];
        int deg = min(degc, BUCKET);
        float di = rsqrtf((float)degc + 1.0f);
        const unsigned short* cb = col + (size_t)node * BUCKET;
        float acc[8];
        {
            ushort8 sv = *reinterpret_cast<const ushort8*>(V + (size_t)node * 128 + d8);
#pragma unroll
            for (int i = 0; i < 8; ++i) acc[i] = di * bf2f(sv[i]);
        }
        int j = 0;
        for (; j + 3 < deg; j += 4) {
            ushort4 c4 = *reinterpret_cast<const ushort4*>(cb + j);
            int s0 = c4.x, s1 = c4.y, s2 = c4.z, s3 = c4.w;
            float w0 = rsqrtf((float)cnt[s0] + 1.0f);
            float w1 = rsqrtf((float)cnt[s1] + 1.0f);
            float w2 = rsqrtf((float)cnt[s2] + 1.0f);
            float w3 = rsqrtf((float)cnt[s3] + 1.0f);
            ushort8 v0 = *reinterpret_cast<const ushort8*>(V + (size_t)s0 * 128 + d8);
            ushort8 v1 = *reinterpret_cast<const ushort8*>(V + (size_t)s1 * 128 + d8);
            ushort8 v2 = *reinterpret_cast<const ushort8*>(V + (size_t)s2 * 128 + d8);
            ushort8 v3 = *reinterpret_cast<const ushort8*>(V + (size_t)s3 * 128 + d8);
#pragma unroll
            for (int i = 0; i < 8; ++i)
                acc[i] += (w0 * bf2f(v0[i]) + w1 * bf2f(v1[i])) +
                          (w2 * bf2f(v2[i]) + w3 * bf2f(v3[i]));
        }
        for (; j < deg; ++j) {
            int si = cb[j];
            float w = rsqrtf((float)cnt[si] + 1.0f);
            ushort8 v = *reinterpret_cast<const ushort8*>(V + (size_t)si * 128 + d8);
#pragma unroll
            for (int i = 0; i < 8; ++i) acc[i] += w * bf2f(v[i]);
        }
#pragma unroll
        for (int i = 0; i < 8; ++i)
            hS[ln][d8 + i] = fmaxf(di * acc[i] + b0v[d8 + i], 0.f);
    } else {
#pragma unroll
        for (int i = 0; i < 8; ++i) hS[ln][d8 + i] = 0.f;
    }
    __syncthreads();

    const int c0 = (tx & 15) * 4;
    float a0 = 0.f, a1 = 0.f, a2 = 0.f, a3 = 0.f;
#pragma unroll 4
    for (int k = 0; k < 128; ++k) {
        float hv = hS[ln][k];
        float4 w = *reinterpret_cast<const float4*>(&W1s[k * 64 + c0]);
        a0 += hv * w.x; a1 += hv * w.y; a2 += hv * w.z; a3 += hv * w.w;
    }
    if (node < n) {
        ushort4 o = make_ushort4(f2bf(a0), f2bf(a1), f2bf(a2), f2bf(a3));
        *reinterpret_cast<ushort4*>(HW + (size_t)node * 64 + c0) = o;
    }
}

// ---------------- final aggregation: out = agg(HW) + b1 ----------------

template <int DIM, bool RELU>
__global__ __launch_bounds__(256) void k_agg(const unsigned short* __restrict__ V,
                                             const int* __restrict__ cnt,
                                             const unsigned short* __restrict__ col,
                                             const float* __restrict__ bias,
                                             float* __restrict__ out, int n) {
    constexpr int TPN = DIM / 8;
    constexpr int NPBk = 256 / TPN;
    int node = blockIdx.x * NPBk + threadIdx.x / TPN;
    int d8 = (threadIdx.x % TPN) * 8;
    if (node >= n) return;
    int degc = cnt[node];
    int deg = min(degc, BUCKET);
    float di = rsqrtf((float)degc + 1.0f);
    const unsigned short* cb = col + (size_t)node * BUCKET;
    float acc[8];
    {
        ushort8 sv = *reinterpret_cast<const ushort8*>(V + (size_t)node * DIM + d8);
#pragma unroll
        for (int i = 0; i < 8; ++i) acc[i] = di * bf2f(sv[i]);
    }
    int j = 0;
    for (; j + 3 < deg; j += 4) {
        ushort4 c4 = *reinterpret_cast<const ushort4*>(cb + j);
        int s0 = c4.x, s1 = c4.y, s2 = c4.z, s3 = c4.w;
        float w0 = rsqrtf((float)cnt[s0] + 1.0f);
        float w1 = rsqrtf((float)cnt[s1] + 1.0f);
        float w2 = rsqrtf((float)cnt[s2] + 1.0f);
        float w3 = rsqrtf((float)cnt[s3] + 1.0f);
        ushort8 v0 = *reinterpret_cast<const ushort8*>(V + (size_t)s0 * DIM + d8);
        ushort8 v1 = *reinterpret_cast<const ushort8*>(V + (size_t)s1 * DIM + d8);
        ushort8 v2 = *reinterpret_cast<const ushort8*>(V + (size_t)s2 * DIM + d8);
        ushort8 v3 = *reinterpret_cast<const ushort8*>(V + (size_t)s3 * DIM + d8);
#pragma unroll
        for (int i = 0; i < 8; ++i)
            acc[i] += (w0 * bf2f(v0[i]) + w1 * bf2f(v1[i])) +
                      (w2 * bf2f(v2[i]) + w3 * bf2f(v3[i]));
    }
    for (; j < deg; ++j) {
        int si = cb[j];
        float w = rsqrtf((float)cnt[si] + 1.0f);
        ushort8 v = *reinterpret_cast<const ushort8*>(V + (size_t)si * DIM + d8);
#pragma unroll
        for (int i = 0; i < 8; ++i) acc[i] += w * bf2f(v[i]);
    }
    float ob[8];
#pragma unroll
    for (int i = 0; i < 8; ++i) {
        float v = di * acc[i] + bias[d8 + i];
        ob[i] = RELU ? fmaxf(v, 0.f) : v;
    }
    float4* op = reinterpret_cast<float4*>(out + (size_t)node * DIM + d8);
    op[0] = make_float4(ob[0], ob[1], ob[2], ob[3]);
    op[1] = make_float4(ob[4], ob[5], ob[6], ob[7]);
}

// ---------------- launch ----------------

extern "C" void kernel_launch(void* const* d_in, const int* in_sizes, int n_in,
                              void* d_out, int out_size, void* d_ws, size_t ws_size,
                              hipStream_t stream) {
    const int n  = in_sizes[0];          // 50000 (< 65536: ushort cols)
    const int nE = in_sizes[1] / 2;      // 800000

    const int*   E  = (const int*)d_in[1];
    const float* X  = (const float*)d_in[2];
    const float* W0 = (const float*)d_in[3];
    const float* b0 = (const float*)d_in[4];
    const float* W1 = (const float*)d_in[5];
    const float* b1 = (const float*)d_in[6];
    float* out = (float*)d_out;

    const int* src = E;
    const int* dst = E + nE;

    char* ws = (char*)d_ws;
    int*            cntP = (int*)(ws + 0x000000);            // 800 KB (stride-4)
    int*            cnt  = (int*)(ws + 0x100000);            // 200 KB dense
    unsigned short* col  = (unsigned short*)(ws + 0x140000); // 6.4 MB
    unsigned short* XW   = (unsigned short*)(ws + 0x800000); // 12.8 MB bf16
    unsigned short* HW   = (unsigned short*)(ws + 0x1500000);// 6.4 MB bf16

    const int nChunk = (nE + 2047) / 2048;   // 391 (8 edges/thread per chunk)
    const int gBuild = nChunk * 8;           // 3128 (range = bid&7)

    k_zero<<<(n * 4 + 255) / 256, 256, 0, stream>>>(cntP, n * 4);
    k_build<<<gBuild, 256, 0, stream>>>(src, dst, cntP, col, nE, n);
    k_pack<<<(n + 255) / 256, 256, 0, stream>>>(cntP, cnt, n);

    // layer 0 GEMM: XW = bf16(X @ W0)
    k_gemm<128><<<(n + 63) / 64, 256, 0, stream>>>(X, W0, XW, n);

    // fused: H = relu(agg(XW)+b0) in LDS; HW = H @ W1
    k_aggmm<<<(n + 31) / 32, 512, 0, stream>>>(XW, cnt, col, b0, W1, HW, n);

    // out = agg(HW) + b1
    k_agg<64, false><<<(n + 31) / 32, 256, 0, stream>>>(HW, cnt, col, b1, out, n);
}